// Round 12
// baseline (205.151 us; speedup 1.0000x reference)
//
#include <hip/hip_runtime.h>
#include <math.h>

// ---------------------------------------------------------------------------
// Encoder_Flows on MI355X — 4 dispatches.
//  D1 prep     : weight cvt (blocks 32-351) + proj1 dbuf -> YT1 (blocks 0-31)
//                + tuple scalar + zero spin counter.
//  D2 main1    : 1024x32-row blocks (R10 core, 2-barrier staged): scan1(heads)
//                + flow@wr1^T + bias(+agg) + L2-norm -> x1 bf16 (ALL rows).
//  D3 combo    : blocks 0-991 = TAIL rows [1024+]: L2 -> L3 -> L4 fused,
//                x2/x3 kept in LDS (saves 48MB x-traffic, 2 dispatch floors);
//                blocks 992-1023 = proj2 (x1[:1024]@wl2^T -> YT2), hidden
//                under the tail. Race-free: proj2 reads only D2's output.
//  D4 headchain: 32 blocks (co-resident by capacity), 5 spin-fenced phases:
//                head-L2 -> proj3 -> head-L3 -> proj4 -> head-L4 -> out[:1024].
// All GEMMs: R10's proven staged bf16-MFMA cores (coalesced reg->swizzled LDS).
// ---------------------------------------------------------------------------

typedef __attribute__((ext_vector_type(8))) short short8;
typedef __attribute__((ext_vector_type(4))) float f32x4;

constexpr int NROWS = 32768;
constexpr int KROWS = 1024;

static __device__ __forceinline__ unsigned short f2bf(float f) {
    unsigned int u = __float_as_uint(f);
    return (unsigned short)((u + 0x7fffu + ((u >> 16) & 1u)) >> 16);
}

// ---- register staging helpers (tile ROWS x 64, XOR-swizzled LDS) ----------
template<int ROWS>
struct RegsBF {
    short8 v[ROWS / 32];
    __device__ __forceinline__ void load(const unsigned short* src, int ld,
                                         int r0, int k0, int t) {
#pragma unroll
        for (int j = 0; j < ROWS / 32; ++j) {
            int idx = j * 256 + t; int r = idx >> 3, f = idx & 7;
            v[j] = *reinterpret_cast<const short8*>(
                src + (size_t)(r0 + r) * ld + k0 + f * 8);
        }
    }
    __device__ __forceinline__ void store(unsigned short* buf, int t) {
#pragma unroll
        for (int j = 0; j < ROWS / 32; ++j) {
            int idx = j * 256 + t; int r = idx >> 3, f = idx & 7;
            int off = (r * 128 + f * 16) ^ ((r & 7) << 4);
            *reinterpret_cast<short8*>((char*)buf + off) = v[j];
        }
    }
};

template<int ROWS>
struct RegsF32 {
    float4 v[ROWS / 16];
    __device__ __forceinline__ void load(const float* src, int ld,
                                         int r0, int k0, int t) {
#pragma unroll
        for (int j = 0; j < ROWS / 32; ++j) {
            int idx = j * 256 + t; int r = idx >> 3, f = idx & 7;
            const float* p = src + (size_t)(r0 + r) * ld + k0 + f * 8;
            v[2 * j]     = *reinterpret_cast<const float4*>(p);
            v[2 * j + 1] = *reinterpret_cast<const float4*>(p + 4);
        }
    }
    __device__ __forceinline__ void store(unsigned short* buf, int t) {
#pragma unroll
        for (int j = 0; j < ROWS / 32; ++j) {
            int idx = j * 256 + t; int r = idx >> 3, f = idx & 7;
            float4 a = v[2 * j], b = v[2 * j + 1];
            short8 s;
            s[0] = (short)f2bf(a.x); s[1] = (short)f2bf(a.y);
            s[2] = (short)f2bf(a.z); s[3] = (short)f2bf(a.w);
            s[4] = (short)f2bf(b.x); s[5] = (short)f2bf(b.y);
            s[6] = (short)f2bf(b.z); s[7] = (short)f2bf(b.w);
            int off = (r * 128 + f * 16) ^ ((r & 7) << 4);
            *reinterpret_cast<short8*>((char*)buf + off) = s;
        }
    }
};

// ---- per-tile fragment read + MFMA (swizzled LDS, BM=32) -------------------
template<int WM, int WN, int FM>
__device__ __forceinline__ void mfma_tile(const unsigned short* Abuf,
    const unsigned short* Bbuf, f32x4 (&acc)[FM][4], int wr_, int wc, int lane)
{
#pragma unroll
    for (int kk = 0; kk < 2; ++kk) {
        short8 a[FM], b[4];
#pragma unroll
        for (int fi = 0; fi < FM; ++fi) {
            const int rA = wr_ * (32 / WM) + fi * 16 + (lane & 15);
            const int off = (rA * 128 + kk * 64 + (lane >> 4) * 16) ^ ((rA & 7) << 4);
            a[fi] = *reinterpret_cast<const short8*>((const char*)Abuf + off);
        }
#pragma unroll
        for (int fj = 0; fj < 4; ++fj) {
            const int rB = wc * 64 + fj * 16 + (lane & 15);
            const int off = (rB * 128 + kk * 64 + (lane >> 4) * 16) ^ ((rB & 7) << 4);
            b[fj] = *reinterpret_cast<const short8*>((const char*)Bbuf + off);
        }
#pragma unroll
        for (int fi = 0; fi < FM; ++fi)
#pragma unroll
            for (int fj = 0; fj < 4; ++fj)
                acc[fi][fj] = __builtin_amdgcn_mfma_f32_16x16x32_bf16(
                    a[fi], b[fj], acc[fi][fj], 0, 0, 0);
    }
}

// ---- 2-barrier staged GEMM: acc = A[32 x din] @ W[DOUT x din]^T ------------
template<int DOUT, bool AFP32>
__device__ __forceinline__ void bulk_gemm(const void* __restrict__ Av,
    const unsigned short* __restrict__ W, f32x4 (&acc)[DOUT / 128][4],
    unsigned short* Abuf, unsigned short* Bbuf, int din, int t)
{
    constexpr int WN = DOUT / 64, WM = 4 / WN, FM = DOUT / 128;
    const int wv = t >> 6, lane = t & 63, wr_ = wv / WN, wc = wv % WN;
    const int nt = din >> 6;
#pragma unroll
    for (int fi = 0; fi < FM; ++fi)
#pragma unroll
        for (int fj = 0; fj < 4; ++fj) acc[fi][fj] = (f32x4){0.f, 0.f, 0.f, 0.f};

    RegsF32<32> arf; RegsBF<32> arb; RegsBF<DOUT> brg;
    if (AFP32) arf.load((const float*)Av, din, 0, 0, t);
    else       arb.load((const unsigned short*)Av, din, 0, 0, t);
    brg.load(W, din, 0, 0, t);
    for (int kt = 0; kt < nt; ++kt) {
        if (kt) __syncthreads();
        if (AFP32) arf.store(Abuf, t); else arb.store(Abuf, t);
        brg.store(Bbuf, t);
        __syncthreads();
        if (kt + 1 < nt) {
            const int kn = (kt + 1) * 64;
            if (AFP32) arf.load((const float*)Av, din, 0, kn, t);
            else       arb.load((const unsigned short*)Av, din, 0, kn, t);
            brg.load(W, din, 0, kn, t);
        }
        mfma_tile<WM, WN, FM>(Abuf, Bbuf, acc, wr_, wc, lane);
    }
}

// ---- A from swizzled LDS xbuf (stride DIN), B staged from global -----------
template<int DIN, int DOUT>
__device__ __forceinline__ void lds_gemm(const unsigned short* __restrict__ xbuf,
    const unsigned short* __restrict__ W, f32x4 (&acc)[DOUT / 128][4],
    unsigned short* Bbuf, int t)
{
    constexpr int WN = DOUT / 64, WM = 4 / WN, FM = DOUT / 128, NT = DIN / 64;
    const int wv = t >> 6, lane = t & 63, wr_ = wv / WN, wc = wv % WN;
#pragma unroll
    for (int fi = 0; fi < FM; ++fi)
#pragma unroll
        for (int fj = 0; fj < 4; ++fj) acc[fi][fj] = (f32x4){0.f, 0.f, 0.f, 0.f};
    RegsBF<DOUT> brg;
    brg.load(W, DIN, 0, 0, t);
    for (int kt = 0; kt < NT; ++kt) {
        if (kt) __syncthreads();
        brg.store(Bbuf, t);
        __syncthreads();
        if (kt + 1 < NT) brg.load(W, DIN, 0, (kt + 1) * 64, t);
#pragma unroll
        for (int kk = 0; kk < 2; ++kk) {
            short8 a[FM], b[4];
            const int k0 = kt * 64 + kk * 32 + ((lane >> 4) << 3);
#pragma unroll
            for (int fi = 0; fi < FM; ++fi) {
                const int rA = wr_ * (32 / WM) + fi * 16 + (lane & 15);
                const int off = ((rA * DIN + k0) * 2) ^ ((rA & 7) << 4);
                a[fi] = *reinterpret_cast<const short8*>((const char*)xbuf + off);
            }
#pragma unroll
            for (int fj = 0; fj < 4; ++fj) {
                const int rB = wc * 64 + fj * 16 + (lane & 15);
                const int off = (rB * 128 + kk * 64 + (lane >> 4) * 16) ^ ((rB & 7) << 4);
                b[fj] = *reinterpret_cast<const short8*>((const char*)Bbuf + off);
            }
#pragma unroll
            for (int fi = 0; fi < FM; ++fi)
#pragma unroll
                for (int fj = 0; fj < 4; ++fj)
                    acc[fi][fj] = __builtin_amdgcn_mfma_f32_16x16x32_bf16(
                        a[fi], b[fj], acc[fi][fj], 0, 0, 0);
        }
    }
}

// ---- scan-GEMM: agg = (L @ Y)/cnt from bf16 Y^T (DOUT x 1024) --------------
template<int DOUT>
__device__ __forceinline__ void scan_agg(const unsigned short* __restrict__ YT,
    int i0, f32x4 (&agg)[DOUT / 128][4], unsigned short* Bbuf, int t)
{
    constexpr int WN = DOUT / 64, WM = 4 / WN, FM = DOUT / 128;
    const int wv = t >> 6, lane = t & 63, wr_ = wv / WN, wc = wv % WN;
#pragma unroll
    for (int fi = 0; fi < FM; ++fi)
#pragma unroll
        for (int fj = 0; fj < 4; ++fj) agg[fi][fj] = (f32x4){0.f, 0.f, 0.f, 0.f};
    const int nt2 = (i0 + 95) >> 6;
    RegsBF<DOUT> sb;
    sb.load(YT, KROWS, 0, 0, t);
    for (int kt = 0; kt < nt2; ++kt) {
        if (kt) __syncthreads();
        sb.store(Bbuf, t);
        __syncthreads();
        if (kt + 1 < nt2) sb.load(YT, KROWS, 0, (kt + 1) * 64, t);
#pragma unroll
        for (int kk = 0; kk < 2; ++kk) {
            const int jb = kt * 64 + kk * 32 + ((lane >> 4) << 3);
            short8 a[FM], b[4];
#pragma unroll
            for (int fi = 0; fi < FM; ++fi) {
                const int irow = i0 + wr_ * (32 / WM) + fi * 16 + (lane & 15);
#pragma unroll
                for (int e = 0; e < 8; ++e)
                    a[fi][e] = (short)((jb + e < irow) ? 0x3F80 : 0);
            }
#pragma unroll
            for (int fj = 0; fj < 4; ++fj) {
                const int rB = wc * 64 + fj * 16 + (lane & 15);
                const int off = (rB * 128 + kk * 64 + (lane >> 4) * 16) ^ ((rB & 7) << 4);
                b[fj] = *reinterpret_cast<const short8*>((const char*)Bbuf + off);
            }
#pragma unroll
            for (int fi = 0; fi < FM; ++fi)
#pragma unroll
                for (int fj = 0; fj < 4; ++fj)
                    agg[fi][fj] = __builtin_amdgcn_mfma_f32_16x16x32_bf16(
                        a[fi], b[fj], agg[fi][fj], 0, 0, 0);
        }
    }
#pragma unroll
    for (int fi = 0; fi < FM; ++fi)
#pragma unroll
        for (int reg = 0; reg < 4; ++reg) {
            const int i_abs = i0 + wr_ * (32 / WM) + fi * 16 + ((lane >> 4) << 2) + reg;
            const float inv = 1.0f / (float)(i_abs > 1 ? i_abs : 1);
#pragma unroll
            for (int fj = 0; fj < 4; ++fj) agg[fi][fj][reg] *= inv;
        }
    __syncthreads();                            // free Bbuf
}

// ---- bias(+agg) add + row L2-norm across block ------------------------------
template<int DOUT>
__device__ __forceinline__ void norm_rows(f32x4 (&acc)[DOUT / 128][4],
    const float* __restrict__ bias, const f32x4 (*agg)[4],
    float* ssred, int t, float (&inv)[DOUT / 128][4])
{
    constexpr int WN = DOUT / 64, WM = 4 / WN, FM = DOUT / 128;
    const int wv = t >> 6, lane = t & 63, wr_ = wv / WN, wc = wv % WN;
    float bb[4];
#pragma unroll
    for (int fj = 0; fj < 4; ++fj) bb[fj] = bias[wc * 64 + fj * 16 + (lane & 15)];
#pragma unroll
    for (int fi = 0; fi < FM; ++fi)
#pragma unroll
        for (int fj = 0; fj < 4; ++fj)
#pragma unroll
            for (int reg = 0; reg < 4; ++reg) {
                float v = acc[fi][fj][reg] + bb[fj];
                if (agg) v += agg[fi][fj][reg];
                acc[fi][fj][reg] = v;
            }
#pragma unroll
    for (int fi = 0; fi < FM; ++fi)
#pragma unroll
        for (int reg = 0; reg < 4; ++reg) {
            float s = 0.f;
#pragma unroll
            for (int fj = 0; fj < 4; ++fj) { float v = acc[fi][fj][reg]; s += v * v; }
#pragma unroll
            for (int m = 8; m >= 1; m >>= 1) s += __shfl_xor(s, m);
            if ((lane & 15) == 0) {
                const int rl = wr_ * (32 / WM) + fi * 16 + ((lane >> 4) << 2) + reg;
                ssred[wc * 32 + rl] = s;
            }
        }
    __syncthreads();
#pragma unroll
    for (int fi = 0; fi < FM; ++fi)
#pragma unroll
        for (int reg = 0; reg < 4; ++reg) {
            const int rl = wr_ * (32 / WM) + fi * 16 + ((lane >> 4) << 2) + reg;
            float s = 0.f;
#pragma unroll
            for (int c = 0; c < WN; ++c) s += ssred[c * 32 + rl];
            inv[fi][reg] = 1.0f / fmaxf(sqrtf(s), 1e-12f);
        }
}

// ---- store normalized rows: LDS xbuf (swizzled) / global bf16 / fp32+relu --
template<int DOUT>
__device__ __forceinline__ void storeX_lds(const f32x4 (&acc)[DOUT / 128][4],
    const float (&inv)[DOUT / 128][4], unsigned short* xbuf, int t)
{
    constexpr int WN = DOUT / 64, WM = 4 / WN, FM = DOUT / 128;
    const int wv = t >> 6, lane = t & 63, wr_ = wv / WN, wc = wv % WN;
#pragma unroll
    for (int fi = 0; fi < FM; ++fi)
#pragma unroll
        for (int fj = 0; fj < 4; ++fj)
#pragma unroll
            for (int reg = 0; reg < 4; ++reg) {
                const int rl = wr_ * (32 / WM) + fi * 16 + ((lane >> 4) << 2) + reg;
                const int cl = wc * 64 + fj * 16 + (lane & 15);
                const int off = ((rl * DOUT + cl) * 2) ^ ((rl & 7) << 4);
                *reinterpret_cast<unsigned short*>((char*)xbuf + off) =
                    f2bf(acc[fi][fj][reg] * inv[fi][reg]);
            }
}

template<int DOUT>
__device__ __forceinline__ void storeX_glb(const f32x4 (&acc)[DOUT / 128][4],
    const float (&inv)[DOUT / 128][4], unsigned short* dst, int i0, int t)
{
    constexpr int WN = DOUT / 64, WM = 4 / WN, FM = DOUT / 128;
    const int wv = t >> 6, lane = t & 63, wr_ = wv / WN, wc = wv % WN;
#pragma unroll
    for (int fi = 0; fi < FM; ++fi)
#pragma unroll
        for (int fj = 0; fj < 4; ++fj)
#pragma unroll
            for (int reg = 0; reg < 4; ++reg) {
                const int rl = wr_ * (32 / WM) + fi * 16 + ((lane >> 4) << 2) + reg;
                const int cl = wc * 64 + fj * 16 + (lane & 15);
                dst[(size_t)(i0 + rl) * DOUT + cl] =
                    f2bf(acc[fi][fj][reg] * inv[fi][reg]);
            }
}

template<int DOUT>
__device__ __forceinline__ void storeOut(const f32x4 (&acc)[DOUT / 128][4],
    const float (&inv)[DOUT / 128][4], float* out, int i0, int t)
{
    constexpr int WN = DOUT / 64, WM = 4 / WN, FM = DOUT / 128;
    const int wv = t >> 6, lane = t & 63, wr_ = wv / WN, wc = wv % WN;
#pragma unroll
    for (int fi = 0; fi < FM; ++fi)
#pragma unroll
        for (int fj = 0; fj < 4; ++fj)
#pragma unroll
            for (int reg = 0; reg < 4; ++reg) {
                const int rl = wr_ * (32 / WM) + fi * 16 + ((lane >> 4) << 2) + reg;
                const int cl = wc * 64 + fj * 16 + (lane & 15);
                out[(size_t)(i0 + rl) * 256 + cl] =
                    fmaxf(acc[fi][fj][reg] * inv[fi][reg], 0.f);
            }
}

// ---- staged proj: YT[:, i0:i0+32] = (X[i0:i0+32] @ W^T)^T -------------------
template<int DIN, int DOUT>
__device__ __forceinline__ void proj_2b(const unsigned short* __restrict__ X,
    const unsigned short* __restrict__ W, unsigned short* __restrict__ YT,
    int i0, unsigned short* Abuf, unsigned short* Bbuf, int t)
{
    constexpr int WN = DOUT / 64, WM = 4 / WN, FM = DOUT / 128;
    const int wv = t >> 6, lane = t & 63, wr_ = wv / WN, wc = wv % WN;
    f32x4 acc[FM][4];
    bulk_gemm<DOUT, false>(X + (size_t)i0 * DIN, W, acc, Abuf, Bbuf, DIN, t);
#pragma unroll
    for (int fi = 0; fi < FM; ++fi)
#pragma unroll
        for (int fj = 0; fj < 4; ++fj) {
            const int rl0 = wr_ * (32 / WM) + fi * 16 + ((lane >> 4) << 2);
            const int cl  = wc * 64 + fj * 16 + (lane & 15);
            ushort4 y;
            y.x = f2bf(acc[fi][fj][0]); y.y = f2bf(acc[fi][fj][1]);
            y.z = f2bf(acc[fi][fj][2]); y.w = f2bf(acc[fi][fj][3]);
            *reinterpret_cast<ushort4*>(YT + (size_t)cl * KROWS + i0 + rl0) = y;
        }
}

// ---- capacity-safe grid barrier (grid must be <= 256 blocks) ---------------
__device__ __forceinline__ void gridbar(unsigned int* cnt, unsigned int phase,
                                        int nblocks) {
    __syncthreads();
    if (threadIdx.x == 0) {
        __threadfence();
        atomicAdd(cnt, 1u);
        while (__hip_atomic_load(cnt, __ATOMIC_ACQUIRE,
                                 __HIP_MEMORY_SCOPE_AGENT) < phase * nblocks)
            __builtin_amdgcn_s_sleep(2);
    }
    __syncthreads();
}

// ---------------------------------------------------------------------------
// D1 prep: proj1 (dbuf, R10) + weight cvt + scalar + counter zero.
// ---------------------------------------------------------------------------
__global__ __launch_bounds__(256, 2)
void prep_kernel(const float* __restrict__ flow, const float* __restrict__ wl1,
                 const float* __restrict__ wr1, const float* __restrict__ wl2,
                 const float* __restrict__ wr2, const float* __restrict__ wl3,
                 const float* __restrict__ wr3, const float* __restrict__ wl4,
                 const float* __restrict__ wr4,
                 unsigned short* __restrict__ wbf,
                 unsigned short* __restrict__ YT1, float* __restrict__ outscalar,
                 unsigned int* __restrict__ cnt)
{
    __shared__ unsigned short Ab0[32 * 64], Ab1[32 * 64];
    __shared__ unsigned short Bb0[128 * 64], Bb1[128 * 64];
    const int t = threadIdx.x, bid = blockIdx.x;
    if (bid >= 32) {
        if (bid == 32 && t == 0) { outscalar[0] = 1.0f; cnt[0] = 0u; }
        int g = (bid - 32) * 1024 + t * 4;
        const float* src; int off;
        if      (g < 131072) { src = wr1; off = g; }
        else if (g < 163840) { src = wl2; off = g - 131072; }
        else if (g < 196608) { src = wr2; off = g - 163840; }
        else if (g < 229376) { src = wl3; off = g - 196608; }
        else if (g < 262144) { src = wr3; off = g - 229376; }
        else if (g < 294912) { src = wl4; off = g - 262144; }
        else                 { src = wr4; off = g - 294912; }
        float4 v = *reinterpret_cast<const float4*>(src + off);
        ushort4 o4;
        o4.x = f2bf(v.x); o4.y = f2bf(v.y); o4.z = f2bf(v.z); o4.w = f2bf(v.w);
        *reinterpret_cast<ushort4*>(wbf + g) = o4;
        return;
    }
    // proj1 (dbuf pipeline, fp32 A and B) — R10 body
    const int i0 = bid * 32, wv = t >> 6, lane = t & 63;
    const int wr_ = wv >> 1, wc = wv & 1;      // DOUT=128
    f32x4 acc[1][4];
#pragma unroll
    for (int fj = 0; fj < 4; ++fj) acc[0][fj] = (f32x4){0.f, 0.f, 0.f, 0.f};
    RegsF32<32> ar; RegsF32<128> br;
    ar.load(flow, 1024, i0, 0, t);
    br.load(wl1, 1024, 0, 0, t);
    ar.store(Ab0, t); br.store(Bb0, t);
    ar.load(flow, 1024, i0, 64, t);
    br.load(wl1, 1024, 0, 64, t);
    __syncthreads();
    for (int kt = 0; kt < 16; ++kt) {
        const unsigned short* Ac = (kt & 1) ? Ab1 : Ab0;
        const unsigned short* Bc = (kt & 1) ? Bb1 : Bb0;
        mfma_tile<2, 2, 1>(Ac, Bc, acc, wr_, wc, lane);
        if (kt + 1 < 16) {
            unsigned short* An = (kt & 1) ? Ab0 : Ab1;
            unsigned short* Bn = (kt & 1) ? Bb0 : Bb1;
            ar.store(An, t); br.store(Bn, t);
            if (kt + 2 < 16) {
                ar.load(flow, 1024, i0, (kt + 2) * 64, t);
                br.load(wl1, 1024, 0, (kt + 2) * 64, t);
            }
        }
        __syncthreads();
    }
#pragma unroll
    for (int fj = 0; fj < 4; ++fj) {
        const int rl0 = wr_ * 16 + ((lane >> 4) << 2);
        const int cl  = wc * 64 + fj * 16 + (lane & 15);
        ushort4 y;
        y.x = f2bf(acc[0][fj][0]); y.y = f2bf(acc[0][fj][1]);
        y.z = f2bf(acc[0][fj][2]); y.w = f2bf(acc[0][fj][3]);
        *reinterpret_cast<ushort4*>(YT1 + (size_t)cl * KROWS + i0 + rl0) = y;
    }
}

// ---------------------------------------------------------------------------
// D2 main1: 1024 blocks, all rows; scan1(heads) + flow@wr1^T + norm -> x1 bf16.
// ---------------------------------------------------------------------------
__global__ __launch_bounds__(256, 4)
void main1_kernel(const float* __restrict__ flow,
                  const unsigned short* __restrict__ W,
                  const float* __restrict__ bias,
                  const unsigned short* __restrict__ YT1,
                  unsigned short* __restrict__ x1)
{
    __shared__ unsigned short Abuf[32 * 64];
    __shared__ unsigned short Bbuf[128 * 64];
    __shared__ float ssred[128];
    const int t = threadIdx.x;
    const int i0 = blockIdx.x * 32;
    const bool head = (i0 < KROWS);

    f32x4 agg[1][4];
#pragma unroll
    for (int fj = 0; fj < 4; ++fj) agg[0][fj] = (f32x4){0.f, 0.f, 0.f, 0.f};
    if (head) scan_agg<128>(YT1, i0, agg, Bbuf, t);

    f32x4 acc[1][4];
    bulk_gemm<128, true>(flow + (size_t)i0 * 1024, W, acc, Abuf, Bbuf, 1024, t);
    float inv[1][4];
    norm_rows<128>(acc, bias, head ? &agg[0] : nullptr, ssred, t, inv);
    storeX_glb<128>(acc, inv, x1, i0, t);
}

// ---------------------------------------------------------------------------
// D3 combo: blocks 0-991 tail L2->L3->L4 (x2/x3 in LDS); 992-1023 proj2.
// ---------------------------------------------------------------------------
__global__ __launch_bounds__(256, 3)
void combo_kernel(const unsigned short* __restrict__ x1,
                  const unsigned short* __restrict__ wr2b, const float* __restrict__ bl2,
                  const unsigned short* __restrict__ wr3b, const float* __restrict__ bl3,
                  const unsigned short* __restrict__ wr4b, const float* __restrict__ bl4,
                  const unsigned short* __restrict__ wl2b,
                  unsigned short* __restrict__ YT2,
                  float* __restrict__ out)
{
    __shared__ unsigned short Abuf[32 * 64];
    __shared__ unsigned short Bbuf[256 * 64];
    __shared__ unsigned short xbuf[32 * 256];
    __shared__ float ssred[128];
    const int t = threadIdx.x, bid = blockIdx.x;

    if (bid >= 992) {                           // proj2 rider blocks
        proj_2b<128, 256>(x1, wl2b, YT2, (bid - 992) * 32, Abuf, Bbuf, t);
        return;
    }
    const int i0 = KROWS + bid * 32;            // tail rows only
    // L2: x1 -> x2 (LDS)
    f32x4 acc2[2][4];
    bulk_gemm<256, false>(x1 + (size_t)i0 * 128, wr2b, acc2, Abuf, Bbuf, 128, t);
    float inv2[2][4];
    norm_rows<256>(acc2, bl2, nullptr, ssred, t, inv2);
    storeX_lds<256>(acc2, inv2, xbuf, t);
    __syncthreads();
    // L3: xbuf(256) -> x3
    f32x4 acc3[1][4];
    lds_gemm<256, 128>(xbuf, wr3b, acc3, Bbuf, t);
    float inv3[1][4];
    norm_rows<128>(acc3, bl3, nullptr, ssred, t, inv3);
    __syncthreads();                            // xbuf reads done
    storeX_lds<128>(acc3, inv3, xbuf, t);
    __syncthreads();
    // L4: xbuf(128) -> relu -> out
    f32x4 acc4[2][4];
    lds_gemm<128, 256>(xbuf, wr4b, acc4, Bbuf, t);
    float inv4[2][4];
    norm_rows<256>(acc4, bl4, nullptr, ssred, t, inv4);
    storeOut<256>(acc4, inv4, out, i0, t);
}

// ---------------------------------------------------------------------------
// D4 headchain: 32 blocks (co-resident by capacity), 5 spin-fenced phases.
// ---------------------------------------------------------------------------
__global__ __launch_bounds__(256, 2)
void headchain_kernel(const unsigned short* __restrict__ x1,
    const unsigned short* __restrict__ wr2b, const float* __restrict__ bl2,
    const unsigned short* __restrict__ YT2,
    const unsigned short* __restrict__ wl3b, unsigned short* __restrict__ YT3,
    const unsigned short* __restrict__ wr3b, const float* __restrict__ bl3,
    const unsigned short* __restrict__ wl4b, unsigned short* __restrict__ YT4,
    const unsigned short* __restrict__ wr4b, const float* __restrict__ bl4,
    unsigned short* __restrict__ x2h, unsigned short* __restrict__ x3h,
    float* __restrict__ out, unsigned int* __restrict__ cnt)
{
    __shared__ unsigned short Abuf[32 * 64];
    __shared__ unsigned short Bbuf[256 * 64];
    __shared__ float ssred[128];
    const int t = threadIdx.x;
    const int i0 = blockIdx.x * 32;

    // phase 1: head-L2 -> x2h
    {
        f32x4 agg[2][4];
        scan_agg<256>(YT2, i0, agg, Bbuf, t);
        f32x4 acc[2][4];
        bulk_gemm<256, false>(x1 + (size_t)i0 * 128, wr2b, acc, Abuf, Bbuf, 128, t);
        float inv[2][4];
        norm_rows<256>(acc, bl2, &agg[0], ssred, t, inv);
        storeX_glb<256>(acc, inv, x2h, i0, t);
    }
    gridbar(cnt, 1, 32);
    // phase 2: proj3 -> YT3
    proj_2b<256, 128>(x2h, wl3b, YT3, i0, Abuf, Bbuf, t);
    gridbar(cnt, 2, 32);
    // phase 3: head-L3 -> x3h
    {
        f32x4 agg[1][4];
        scan_agg<128>(YT3, i0, agg, Bbuf, t);
        f32x4 acc[1][4];
        bulk_gemm<128, false>(x2h + (size_t)i0 * 256, wr3b, acc, Abuf, Bbuf, 256, t);
        float inv[1][4];
        norm_rows<128>(acc, bl3, &agg[0], ssred, t, inv);
        storeX_glb<128>(acc, inv, x3h, i0, t);
    }
    gridbar(cnt, 3, 32);
    // phase 4: proj4 -> YT4
    proj_2b<128, 256>(x3h, wl4b, YT4, i0, Abuf, Bbuf, t);
    gridbar(cnt, 4, 32);
    // phase 5: head-L4 -> relu -> out[:1024]
    {
        f32x4 agg[2][4];
        scan_agg<256>(YT4, i0, agg, Bbuf, t);
        f32x4 acc[2][4];
        bulk_gemm<256, false>(x3h + (size_t)i0 * 128, wr4b, acc, Abuf, Bbuf, 128, t);
        float inv[2][4];
        norm_rows<256>(acc, bl4, &agg[0], ssred, t, inv);
        storeOut<256>(acc, inv, out, i0, t);
    }
}

extern "C" void kernel_launch(void* const* d_in, const int* in_sizes, int n_in,
                              void* d_out, int out_size, void* d_ws, size_t ws_size,
                              hipStream_t stream)
{
    const float* flow = (const float*)d_in[0];
    const float* wl1 = (const float*)d_in[1];
    const float* bl1 = (const float*)d_in[2];
    const float* wr1 = (const float*)d_in[3];
    const float* wl2 = (const float*)d_in[4];
    const float* bl2 = (const float*)d_in[5];
    const float* wr2 = (const float*)d_in[6];
    const float* wl3 = (const float*)d_in[7];
    const float* bl3 = (const float*)d_in[8];
    const float* wr3 = (const float*)d_in[9];
    const float* wl4 = (const float*)d_in[10];
    const float* bl4 = (const float*)d_in[11];
    const float* wr4 = (const float*)d_in[12];
    float* out = (float*)d_out;

    char* p = (char*)d_ws;
    unsigned short* wbf = (unsigned short*)p;  p += 1 << 20;
    unsigned short* x1  = (unsigned short*)p;  p += (size_t)NROWS * 128 * 2;
    unsigned short* YT1 = (unsigned short*)p;  p += (size_t)128 * KROWS * 2;
    unsigned short* YT2 = (unsigned short*)p;  p += (size_t)256 * KROWS * 2;
    unsigned short* YT3 = (unsigned short*)p;  p += (size_t)128 * KROWS * 2;
    unsigned short* YT4 = (unsigned short*)p;  p += (size_t)256 * KROWS * 2;
    unsigned short* x2h = (unsigned short*)p;  p += (size_t)KROWS * 256 * 2;
    unsigned short* x3h = (unsigned short*)p;  p += (size_t)KROWS * 128 * 2;
    unsigned int*  cnt  = (unsigned int*)p;

    const unsigned short* wr1b = wbf;
    const unsigned short* wl2b = wbf + 131072;
    const unsigned short* wr2b = wbf + 163840;
    const unsigned short* wl3b = wbf + 196608;
    const unsigned short* wr3b = wbf + 229376;
    const unsigned short* wl4b = wbf + 262144;
    const unsigned short* wr4b = wbf + 294912;

    // D1: cvt + proj1 + scalar + counter zero
    prep_kernel<<<352, 256, 0, stream>>>(flow, wl1, wr1, wl2, wr2, wl3, wr3,
                                         wl4, wr4, wbf, YT1,
                                         out + (size_t)NROWS * 256, cnt);
    // D2: main1 (all rows)
    main1_kernel<<<1024, 256, 0, stream>>>(flow, wr1b, bl1, YT1, x1);
    // D3: tail L2-L4 fused + proj2 riders
    combo_kernel<<<1024, 256, 0, stream>>>(x1, wr2b, bl2, wr3b, bl3, wr4b, bl4,
                                           wl2b, YT2, out);
    // D4: head chain (rows 0-1023) with spin-fenced phases
    headchain_kernel<<<32, 256, 0, stream>>>(x1, wr2b, bl2, YT2, wl3b, YT3,
                                             wr3b, bl3, wl4b, YT4, wr4b, bl4,
                                             x2h, x3h, out, cnt);
}

// Round 13
// 94.543 us; speedup vs baseline: 2.1699x; 2.1699x over previous
//
#include <hip/hip_runtime.h>
#include <math.h>

// ---------------------------------------------------------------------------
// Encoder_Flows on MI355X — 8 dispatches (R10 structure, 112.7us base) +
// per-tile column sums T to kill the scan straggler.
//   proj_L (32 blocks, dbuf): YT_L = (x@wl^T)^T bf16  AND  T_L[m][col] =
//       column sums of tile m's 32 Y rows (fp32, from pre-rounding acc).
//   main_L (1024 blocks): tail = staged GEMM + norm (unchanged R10 core).
//       Head tile m: agg = (P + local)/cnt with P[col]=sum_{m'<m}T[m'][col]
//       (<=31 coalesced fp32 loads) and local = ONE staged triangular step
//       over YT cols [i0&~63, +64) with A=1 iff i0<=j<i. Replaces the
//       up-to-17-step scan-GEMM that stragglers every main dispatch.
// Laws (R3/R6/R7/R8/R9/R12): no spin sync ever; no direct-frag global loads;
// no in-block layer chains; head-extra work must be coalesced + small.
// ---------------------------------------------------------------------------

typedef __attribute__((ext_vector_type(8))) short short8;
typedef __attribute__((ext_vector_type(4))) float f32x4;

constexpr int NROWS = 32768;
constexpr int KROWS = 1024;

static __device__ __forceinline__ unsigned short f2bf(float f) {
    unsigned int u = __float_as_uint(f);
    return (unsigned short)((u + 0x7fffu + ((u >> 16) & 1u)) >> 16);
}

// ---- register staging helpers (tile ROWS x 64, XOR-swizzled LDS) ----------
template<int ROWS>
struct RegsBF {
    short8 v[ROWS / 32];
    __device__ __forceinline__ void load(const unsigned short* src, int ld,
                                         int r0, int k0, int t) {
#pragma unroll
        for (int j = 0; j < ROWS / 32; ++j) {
            int idx = j * 256 + t; int r = idx >> 3, f = idx & 7;
            v[j] = *reinterpret_cast<const short8*>(
                src + (size_t)(r0 + r) * ld + k0 + f * 8);
        }
    }
    __device__ __forceinline__ void store(unsigned short* buf, int t) {
#pragma unroll
        for (int j = 0; j < ROWS / 32; ++j) {
            int idx = j * 256 + t; int r = idx >> 3, f = idx & 7;
            int off = (r * 128 + f * 16) ^ ((r & 7) << 4);
            *reinterpret_cast<short8*>((char*)buf + off) = v[j];
        }
    }
};

template<int ROWS>
struct RegsF32 {
    float4 v[ROWS / 16];
    __device__ __forceinline__ void load(const float* src, int ld,
                                         int r0, int k0, int t) {
#pragma unroll
        for (int j = 0; j < ROWS / 32; ++j) {
            int idx = j * 256 + t; int r = idx >> 3, f = idx & 7;
            const float* p = src + (size_t)(r0 + r) * ld + k0 + f * 8;
            v[2 * j]     = *reinterpret_cast<const float4*>(p);
            v[2 * j + 1] = *reinterpret_cast<const float4*>(p + 4);
        }
    }
    __device__ __forceinline__ void store(unsigned short* buf, int t) {
#pragma unroll
        for (int j = 0; j < ROWS / 32; ++j) {
            int idx = j * 256 + t; int r = idx >> 3, f = idx & 7;
            float4 a = v[2 * j], b = v[2 * j + 1];
            short8 s;
            s[0] = (short)f2bf(a.x); s[1] = (short)f2bf(a.y);
            s[2] = (short)f2bf(a.z); s[3] = (short)f2bf(a.w);
            s[4] = (short)f2bf(b.x); s[5] = (short)f2bf(b.y);
            s[6] = (short)f2bf(b.z); s[7] = (short)f2bf(b.w);
            int off = (r * 128 + f * 16) ^ ((r & 7) << 4);
            *reinterpret_cast<short8*>((char*)buf + off) = s;
        }
    }
};

// ---- per-tile fragment read + MFMA over one 64-k LDS tile ------------------
template<int BM, int WM, int WN, int FM>
__device__ __forceinline__ void mfma_tile(const unsigned short* Abuf,
    const unsigned short* Bbuf, f32x4 (&acc)[FM][4], int wr_, int wc, int lane)
{
#pragma unroll
    for (int kk = 0; kk < 2; ++kk) {
        short8 a[FM], b[4];
#pragma unroll
        for (int fi = 0; fi < FM; ++fi) {
            const int rA = wr_ * (BM / WM) + fi * 16 + (lane & 15);
            const int off = (rA * 128 + kk * 64 + (lane >> 4) * 16) ^ ((rA & 7) << 4);
            a[fi] = *reinterpret_cast<const short8*>((const char*)Abuf + off);
        }
#pragma unroll
        for (int fj = 0; fj < 4; ++fj) {
            const int rB = wc * 64 + fj * 16 + (lane & 15);
            const int off = (rB * 128 + kk * 64 + (lane >> 4) * 16) ^ ((rB & 7) << 4);
            b[fj] = *reinterpret_cast<const short8*>((const char*)Bbuf + off);
        }
#pragma unroll
        for (int fi = 0; fi < FM; ++fi)
#pragma unroll
            for (int fj = 0; fj < 4; ++fj)
                acc[fi][fj] = __builtin_amdgcn_mfma_f32_16x16x32_bf16(
                    a[fi], b[fj], acc[fi][fj], 0, 0, 0);
    }
}

// ---------------------------------------------------------------------------
// Proj body: YT[:, i0:i0+32] = (X[i0..i0+32) @ W^T)^T bf16, dbuf-pipelined,
// plus T[col] = fp32 column sums of this tile's 32 Y rows.
// ---------------------------------------------------------------------------
template<int DIN, int DOUT, bool AFP32, bool BFP32>
__device__ __forceinline__ void proj_dbuf(const void* __restrict__ Xv,
    const void* __restrict__ Wv, unsigned short* __restrict__ YT,
    float* __restrict__ Tg,                     // pre-offset to tile m
    int i0, int t,
    unsigned short* Ab0, unsigned short* Ab1,
    unsigned short* Bb0, unsigned short* Bb1, float* Tred)
{
    constexpr int WN = DOUT / 64, WM = 4 / WN, FM = DOUT / 128, NT = DIN / 64;
    const int wv = t >> 6, lane = t & 63, wr_ = wv / WN, wc = wv % WN;
    f32x4 acc[FM][4];
#pragma unroll
    for (int fi = 0; fi < FM; ++fi)
#pragma unroll
        for (int fj = 0; fj < 4; ++fj) acc[fi][fj] = (f32x4){0.f, 0.f, 0.f, 0.f};

    RegsF32<32>  arf; RegsBF<32>  arb;
    RegsF32<DOUT> brf; RegsBF<DOUT> brb;
    if (AFP32) arf.load((const float*)Xv, DIN, i0, 0, t);
    else       arb.load((const unsigned short*)Xv, DIN, i0, 0, t);
    if (BFP32) brf.load((const float*)Wv, DIN, 0, 0, t);
    else       brb.load((const unsigned short*)Wv, DIN, 0, 0, t);
    if (AFP32) arf.store(Ab0, t); else arb.store(Ab0, t);
    if (BFP32) brf.store(Bb0, t); else brb.store(Bb0, t);
    if (NT > 1) {
        if (AFP32) arf.load((const float*)Xv, DIN, i0, 64, t);
        else       arb.load((const unsigned short*)Xv, DIN, i0, 64, t);
        if (BFP32) brf.load((const float*)Wv, DIN, 0, 64, t);
        else       brb.load((const unsigned short*)Wv, DIN, 0, 64, t);
    }
    __syncthreads();

    for (int kt = 0; kt < NT; ++kt) {
        const unsigned short* Ac = (kt & 1) ? Ab1 : Ab0;
        const unsigned short* Bc = (kt & 1) ? Bb1 : Bb0;
        mfma_tile<32, WM, WN, FM>(Ac, Bc, acc, wr_, wc, lane);
        if (kt + 1 < NT) {
            unsigned short* An = (kt & 1) ? Ab0 : Ab1;
            unsigned short* Bn = (kt & 1) ? Bb0 : Bb1;
            if (AFP32) arf.store(An, t); else arb.store(An, t);
            if (BFP32) brf.store(Bn, t); else brb.store(Bn, t);
            if (kt + 2 < NT) {
                const int kn = (kt + 2) * 64;
                if (AFP32) arf.load((const float*)Xv, DIN, i0, kn, t);
                else       arb.load((const unsigned short*)Xv, DIN, i0, kn, t);
                if (BFP32) brf.load((const float*)Wv, DIN, 0, kn, t);
                else       brb.load((const unsigned short*)Wv, DIN, 0, kn, t);
            }
        }
        __syncthreads();
    }
    // YT epilogue (C/D m89 layout)
#pragma unroll
    for (int fi = 0; fi < FM; ++fi)
#pragma unroll
        for (int fj = 0; fj < 4; ++fj) {
            const int rl0 = wr_ * (32 / WM) + fi * 16 + ((lane >> 4) << 2);
            const int cl  = wc * 64 + fj * 16 + (lane & 15);
            ushort4 y;
            y.x = f2bf(acc[fi][fj][0]); y.y = f2bf(acc[fi][fj][1]);
            y.z = f2bf(acc[fi][fj][2]); y.w = f2bf(acc[fi][fj][3]);
            *reinterpret_cast<ushort4*>(YT + (size_t)cl * KROWS + i0 + rl0) = y;
        }
    // T epilogue: column sums over the 32 rows (fp32, pre-rounding)
    {
        float v[4];
#pragma unroll
        for (int fj = 0; fj < 4; ++fj) {
            float s = 0.f;
#pragma unroll
            for (int fi = 0; fi < FM; ++fi)
#pragma unroll
                for (int reg = 0; reg < 4; ++reg) s += acc[fi][fj][reg];
            s += __shfl_xor(s, 16);             // sum over (lane>>4) row groups
            s += __shfl_xor(s, 32);
            v[fj] = s;
        }
        if (lane < 16) {
#pragma unroll
            for (int fj = 0; fj < 4; ++fj)
                Tred[wr_ * DOUT + wc * 64 + fj * 16 + lane] = v[fj];
        }
        __syncthreads();
        if (t < DOUT) {
            float s = Tred[t];
            if constexpr (WM == 2) s += Tred[DOUT + t];
            Tg[t] = s;
        }
    }
}

// ---------------------------------------------------------------------------
// prep: blocks [0,32) proj1 -> YT1 + T1; blocks [32,352) weight cvt; scalar.
// ---------------------------------------------------------------------------
__global__ __launch_bounds__(256, 2)
void prep_kernel(const float* __restrict__ flow, const float* __restrict__ wl1,
                 const float* __restrict__ wr1, const float* __restrict__ wl2,
                 const float* __restrict__ wr2, const float* __restrict__ wl3,
                 const float* __restrict__ wr3, const float* __restrict__ wl4,
                 const float* __restrict__ wr4,
                 unsigned short* __restrict__ wbf,
                 unsigned short* __restrict__ YT1, float* __restrict__ T1,
                 float* __restrict__ outscalar)
{
    __shared__ unsigned short Ab0[32 * 64], Ab1[32 * 64];
    __shared__ unsigned short Bb0[128 * 64], Bb1[128 * 64];
    __shared__ float Tred[256];
    const int t = threadIdx.x, bid = blockIdx.x;
    if (bid >= 32) {
        if (bid == 32 && t == 0) outscalar[0] = 1.0f;
        int g = (bid - 32) * 1024 + t * 4;
        const float* src; int off;
        if      (g < 131072) { src = wr1; off = g; }
        else if (g < 163840) { src = wl2; off = g - 131072; }
        else if (g < 196608) { src = wr2; off = g - 163840; }
        else if (g < 229376) { src = wl3; off = g - 196608; }
        else if (g < 262144) { src = wr3; off = g - 229376; }
        else if (g < 294912) { src = wl4; off = g - 262144; }
        else                 { src = wr4; off = g - 294912; }
        float4 v = *reinterpret_cast<const float4*>(src + off);
        ushort4 o4;
        o4.x = f2bf(v.x); o4.y = f2bf(v.y); o4.z = f2bf(v.z); o4.w = f2bf(v.w);
        *reinterpret_cast<ushort4*>(wbf + g) = o4;
        return;
    }
    proj_dbuf<1024, 128, true, true>(flow, wl1, YT1, T1 + bid * 128,
                                     bid * 32, t, Ab0, Ab1, Bb0, Bb1, Tred);
}

// ---- proj_L (L2-4): 32 blocks, x bf16 in, bf16 weights --------------------
template<int DIN, int DOUT>
__global__ __launch_bounds__(256, 2)
void proj_kernel(const unsigned short* __restrict__ X,
                 const unsigned short* __restrict__ W,
                 unsigned short* __restrict__ YT, float* __restrict__ T)
{
    __shared__ unsigned short Ab0[32 * 64], Ab1[32 * 64];
    __shared__ unsigned short Bb0[DOUT * 64], Bb1[DOUT * 64];
    __shared__ float Tred[256];
    proj_dbuf<DIN, DOUT, false, false>(X, W, YT, T + blockIdx.x * DOUT,
                                       blockIdx.x * 32, threadIdx.x,
                                       Ab0, Ab1, Bb0, Bb1, Tred);
}

// ---------------------------------------------------------------------------
// main_L (R10 core + light head path).  MODE 1: bf16 out.  MODE 2: relu->fp32.
// ---------------------------------------------------------------------------
template<int DOUT, int BM, int WM, int WN, int MODE, bool AFP32, int MINW>
__global__ __launch_bounds__(256, MINW)
void mfma_gemm(const void* __restrict__ Xv,
               const unsigned short* __restrict__ W,
               const float* __restrict__ bias,
               const unsigned short* __restrict__ YT,  // (DOUT, 1024) bf16
               const float* __restrict__ Tbuf,         // (32, DOUT) fp32
               float* __restrict__ outf,
               unsigned short* __restrict__ outb,
               int din)
{
    constexpr int BN = WN * 64;
    static_assert(BN == DOUT, "block must own full output rows");
    constexpr int FM = BM / (WM * 16);
    __shared__ unsigned short Abuf[BM * 64];
    __shared__ unsigned short Bbuf[BN * 64];
    __shared__ float ssred[WN * BM];

    const int t = threadIdx.x, wvid = t >> 6, lane = t & 63;
    const int wr_ = wvid / WN, wc = wvid % WN;
    const int i0 = blockIdx.x * BM;
    const int nt = din >> 6;
    const bool hasagg = (i0 < KROWS);

    f32x4 agg[FM][4];
#pragma unroll
    for (int fi = 0; fi < FM; ++fi)
#pragma unroll
        for (int fj = 0; fj < 4; ++fj) agg[fi][fj] = (f32x4){0.f, 0.f, 0.f, 0.f};

    float Pv[4] = {0.f, 0.f, 0.f, 0.f};
    if (hasagg) {
        // ---- P[col] = sum_{m'<m} T[m'][col]; 8 independent load chains ----
        const int m = i0 >> 5;
        const int colb = wc * 64 + (lane & 15);
        float Pa[4] = {0.f, 0.f, 0.f, 0.f};
        int mp = 0;
        for (; mp + 1 < m; mp += 2) {
            const float* T0 = Tbuf + (size_t)mp * DOUT + colb;
            const float* T1 = T0 + DOUT;
#pragma unroll
            for (int fj = 0; fj < 4; ++fj) {
                Pv[fj] += T0[fj * 16];
                Pa[fj] += T1[fj * 16];
            }
        }
        if (mp < m) {
            const float* T0 = Tbuf + (size_t)mp * DOUT + colb;
#pragma unroll
            for (int fj = 0; fj < 4; ++fj) Pv[fj] += T0[fj * 16];
        }
#pragma unroll
        for (int fj = 0; fj < 4; ++fj) Pv[fj] += Pa[fj];

        // ---- local triangular: ONE staged step over YT cols [base,base+64) -
        const int base = i0 & ~63;
        RegsBF<BN> sb;
        sb.load(YT, KROWS, 0, base, t);
        sb.store(Bbuf, t);
        __syncthreads();
#pragma unroll
        for (int kk = 0; kk < 2; ++kk) {
            const int jb = base + kk * 32 + ((lane >> 4) << 3);
            short8 a[FM], b[4];
#pragma unroll
            for (int fi = 0; fi < FM; ++fi) {
                const int irow = i0 + wr_ * (BM / WM) + fi * 16 + (lane & 15);
#pragma unroll
                for (int e = 0; e < 8; ++e)
                    a[fi][e] = (short)((jb + e >= i0 && jb + e < irow) ? 0x3F80 : 0);
            }
#pragma unroll
            for (int fj = 0; fj < 4; ++fj) {
                const int rB = wc * 64 + fj * 16 + (lane & 15);
                const int off = (rB * 128 + kk * 64 + (lane >> 4) * 16) ^ ((rB & 7) << 4);
                b[fj] = *reinterpret_cast<const short8*>((const char*)Bbuf + off);
            }
#pragma unroll
            for (int fi = 0; fi < FM; ++fi)
#pragma unroll
                for (int fj = 0; fj < 4; ++fj)
                    agg[fi][fj] = __builtin_amdgcn_mfma_f32_16x16x32_bf16(
                        a[fi], b[fj], agg[fi][fj], 0, 0, 0);
        }
        // combine + divide by cnt = max(i,1)
#pragma unroll
        for (int fi = 0; fi < FM; ++fi)
#pragma unroll
            for (int reg = 0; reg < 4; ++reg) {
                const int i_abs = i0 + wr_ * (BM / WM) + fi * 16 + ((lane >> 4) << 2) + reg;
                const float inv = 1.0f / (float)(i_abs > 1 ? i_abs : 1);
#pragma unroll
                for (int fj = 0; fj < 4; ++fj)
                    agg[fi][fj][reg] = (agg[fi][fj][reg] + Pv[fj]) * inv;
            }
        __syncthreads();                        // Bbuf free before bulk
    }

    // ---- bulk GEMM (R10 2-barrier staged core) ----
    f32x4 acc[FM][4];
#pragma unroll
    for (int fi = 0; fi < FM; ++fi)
#pragma unroll
        for (int fj = 0; fj < 4; ++fj) acc[fi][fj] = (f32x4){0.f, 0.f, 0.f, 0.f};

    RegsBF<BN> brg;
    RegsF32<BM> arf;
    RegsBF<BM> arb;
    if (AFP32) arf.load((const float*)Xv, din, i0, 0, t);
    else       arb.load((const unsigned short*)Xv, din, i0, 0, t);
    brg.load(W, din, 0, 0, t);

    for (int kt = 0; kt < nt; ++kt) {
        if (kt) __syncthreads();
        if (AFP32) arf.store(Abuf, t); else arb.store(Abuf, t);
        brg.store(Bbuf, t);
        __syncthreads();
        if (kt + 1 < nt) {
            int kn = (kt + 1) * 64;
            if (AFP32) arf.load((const float*)Xv, din, i0, kn, t);
            else       arb.load((const unsigned short*)Xv, din, i0, kn, t);
            brg.load(W, din, 0, kn, t);
        }
        mfma_tile<BM, WM, WN, FM>(Abuf, Bbuf, acc, wr_, wc, lane);
    }

    float bb[4];
#pragma unroll
    for (int fj = 0; fj < 4; ++fj) bb[fj] = bias[wc * 64 + fj * 16 + (lane & 15)];

#pragma unroll
    for (int fi = 0; fi < FM; ++fi)
#pragma unroll
        for (int fj = 0; fj < 4; ++fj)
#pragma unroll
            for (int reg = 0; reg < 4; ++reg)
                acc[fi][fj][reg] += bb[fj] + agg[fi][fj][reg];

    float sstot[FM][4];
#pragma unroll
    for (int fi = 0; fi < FM; ++fi)
#pragma unroll
        for (int reg = 0; reg < 4; ++reg) {
            float s = 0.f;
#pragma unroll
            for (int fj = 0; fj < 4; ++fj) {
                float v = acc[fi][fj][reg];
                s += v * v;
            }
#pragma unroll
            for (int m2 = 8; m2 >= 1; m2 >>= 1) s += __shfl_xor(s, m2);
            if ((lane & 15) == 0) {
                int rl = wr_ * (BM / WM) + fi * 16 + ((lane >> 4) << 2) + reg;
                ssred[wc * BM + rl] = s;
            }
        }
    __syncthreads();
#pragma unroll
    for (int fi = 0; fi < FM; ++fi)
#pragma unroll
        for (int reg = 0; reg < 4; ++reg) {
            int rl = wr_ * (BM / WM) + fi * 16 + ((lane >> 4) << 2) + reg;
            float s = 0.f;
#pragma unroll
            for (int c = 0; c < WN; ++c) s += ssred[c * BM + rl];
            sstot[fi][reg] = 1.0f / fmaxf(sqrtf(s), 1e-12f);
        }

#pragma unroll
    for (int fi = 0; fi < FM; ++fi)
#pragma unroll
        for (int fj = 0; fj < 4; ++fj)
#pragma unroll
            for (int reg = 0; reg < 4; ++reg) {
                int rl = wr_ * (BM / WM) + fi * 16 + ((lane >> 4) << 2) + reg;
                int cl = wc * 64 + fj * 16 + (lane & 15);
                float v = acc[fi][fj][reg] * sstot[fi][reg];
                if (MODE == 2) {
                    v = fmaxf(v, 0.f);
                    outf[(size_t)(i0 + rl) * DOUT + cl] = v;
                } else {
                    outb[(size_t)(i0 + rl) * DOUT + cl] = f2bf(v);
                }
            }
}

extern "C" void kernel_launch(void* const* d_in, const int* in_sizes, int n_in,
                              void* d_out, int out_size, void* d_ws, size_t ws_size,
                              hipStream_t stream)
{
    const float* flow = (const float*)d_in[0];
    const float* wl1 = (const float*)d_in[1];
    const float* bl1 = (const float*)d_in[2];
    const float* wr1 = (const float*)d_in[3];
    const float* wl2 = (const float*)d_in[4];
    const float* bl2 = (const float*)d_in[5];
    const float* wr2 = (const float*)d_in[6];
    const float* wl3 = (const float*)d_in[7];
    const float* bl3 = (const float*)d_in[8];
    const float* wr3 = (const float*)d_in[9];
    const float* wl4 = (const float*)d_in[10];
    const float* bl4 = (const float*)d_in[11];
    const float* wr4 = (const float*)d_in[12];
    float* out = (float*)d_out;

    char* p = (char*)d_ws;
    unsigned short* wbf = (unsigned short*)p;  p += 1 << 20;
    unsigned short* xA  = (unsigned short*)p;  p += (size_t)NROWS * 128 * 2;
    unsigned short* xB  = (unsigned short*)p;  p += (size_t)NROWS * 256 * 2;
    unsigned short* YT1 = (unsigned short*)p;  p += (size_t)128 * KROWS * 2;
    unsigned short* YT2 = (unsigned short*)p;  p += (size_t)256 * KROWS * 2;
    unsigned short* YT3 = (unsigned short*)p;  p += (size_t)128 * KROWS * 2;
    unsigned short* YT4 = (unsigned short*)p;  p += (size_t)256 * KROWS * 2;
    float* T1 = (float*)p;                     p += (size_t)32 * 128 * 4;
    float* T2 = (float*)p;                     p += (size_t)32 * 256 * 4;
    float* T3 = (float*)p;                     p += (size_t)32 * 128 * 4;
    float* T4 = (float*)p;

    const unsigned short* wr1b = wbf;
    const unsigned short* wl2b = wbf + 131072;
    const unsigned short* wr2b = wbf + 163840;
    const unsigned short* wl3b = wbf + 196608;
    const unsigned short* wr3b = wbf + 229376;
    const unsigned short* wl4b = wbf + 262144;
    const unsigned short* wr4b = wbf + 294912;

    // D1: cvt + proj1 (+ tuple scalar)
    prep_kernel<<<352, 256, 0, stream>>>(flow, wl1, wr1, wl2, wr2, wl3, wr3,
                                         wl4, wr4, wbf, YT1, T1,
                                         out + (size_t)NROWS * 256);
    // D2: main L1 (din=1024, fp32 A)
    mfma_gemm<128, 32, 2, 2, 1, true , 4><<<1024, 256, 0, stream>>>(
        flow, wr1b, bl1, YT1, T1, nullptr, xA, 1024);
    // D3-4: L2
    proj_kernel<128, 256><<<32, 256, 0, stream>>>(xA, wl2b, YT2, T2);
    mfma_gemm<256, 32, 1, 4, 1, false, 3><<<1024, 256, 0, stream>>>(
        xA, wr2b, bl2, YT2, T2, nullptr, xB, 128);
    // D5-6: L3
    proj_kernel<256, 128><<<32, 256, 0, stream>>>(xB, wl3b, YT3, T3);
    mfma_gemm<128, 32, 2, 2, 1, false, 4><<<1024, 256, 0, stream>>>(
        xB, wr3b, bl3, YT3, T3, nullptr, xA, 256);
    // D7-8: L4 + relu -> fp32 out
    proj_kernel<128, 256><<<32, 256, 0, stream>>>(xA, wl4b, YT4, T4);
    mfma_gemm<256, 32, 1, 4, 2, false, 3><<<1024, 256, 0, stream>>>(
        xA, wr4b, bl4, YT4, T4, out, nullptr, 128);
}

// Round 14
// 90.759 us; speedup vs baseline: 2.2604x; 1.0417x over previous
//
#include <hip/hip_runtime.h>
#include <math.h>

// ---------------------------------------------------------------------------
// Encoder_Flows on MI355X — 5 dispatches (R13 = 94.5us base, 8 dispatches).
//   prep  : blocks 0-31 proj1 (dbuf) -> YT1 + T1; blocks 32-351 weight cvt.
//   main_L: 1024x32-row blocks (R13 core): tail = staged GEMM + norm.
//       Head tile m: agg = (P + local)/cnt  (P from per-tile T sums, local =
//       ONE triangular step) — the R13 straggler fix.  NEW: after storing its
//       own 32 x-rows, a head block __syncthreads (drains stores) and runs
//       the NEXT layer's proj on its own rows via the same staged bulk_gemm
//       (coalesced W_next staging), writing YT_next + T_next. This removes
//       the 3 separate proj dispatches (and their gaps) race-free.
//   R8's failure causes are both fixed here: scan is 1 step (T), proj W is
//   coalesced-staged (not direct-frag).
// Laws: no spin sync; no direct-frag global loads; no in-block layer chains;
// head-extra work must be coalesced + small.
// ---------------------------------------------------------------------------

typedef __attribute__((ext_vector_type(8))) short short8;
typedef __attribute__((ext_vector_type(4))) float f32x4;

constexpr int NROWS = 32768;
constexpr int KROWS = 1024;

static __device__ __forceinline__ unsigned short f2bf(float f) {
    unsigned int u = __float_as_uint(f);
    return (unsigned short)((u + 0x7fffu + ((u >> 16) & 1u)) >> 16);
}

// ---- register staging helpers (tile ROWS x 64, XOR-swizzled LDS) ----------
template<int ROWS>
struct RegsBF {
    short8 v[ROWS / 32];
    __device__ __forceinline__ void load(const unsigned short* src, int ld,
                                         int r0, int k0, int t) {
#pragma unroll
        for (int j = 0; j < ROWS / 32; ++j) {
            int idx = j * 256 + t; int r = idx >> 3, f = idx & 7;
            v[j] = *reinterpret_cast<const short8*>(
                src + (size_t)(r0 + r) * ld + k0 + f * 8);
        }
    }
    __device__ __forceinline__ void store(unsigned short* buf, int t) {
#pragma unroll
        for (int j = 0; j < ROWS / 32; ++j) {
            int idx = j * 256 + t; int r = idx >> 3, f = idx & 7;
            int off = (r * 128 + f * 16) ^ ((r & 7) << 4);
            *reinterpret_cast<short8*>((char*)buf + off) = v[j];
        }
    }
};

template<int ROWS>
struct RegsF32 {
    float4 v[ROWS / 16];
    __device__ __forceinline__ void load(const float* src, int ld,
                                         int r0, int k0, int t) {
#pragma unroll
        for (int j = 0; j < ROWS / 32; ++j) {
            int idx = j * 256 + t; int r = idx >> 3, f = idx & 7;
            const float* p = src + (size_t)(r0 + r) * ld + k0 + f * 8;
            v[2 * j]     = *reinterpret_cast<const float4*>(p);
            v[2 * j + 1] = *reinterpret_cast<const float4*>(p + 4);
        }
    }
    __device__ __forceinline__ void store(unsigned short* buf, int t) {
#pragma unroll
        for (int j = 0; j < ROWS / 32; ++j) {
            int idx = j * 256 + t; int r = idx >> 3, f = idx & 7;
            float4 a = v[2 * j], b = v[2 * j + 1];
            short8 s;
            s[0] = (short)f2bf(a.x); s[1] = (short)f2bf(a.y);
            s[2] = (short)f2bf(a.z); s[3] = (short)f2bf(a.w);
            s[4] = (short)f2bf(b.x); s[5] = (short)f2bf(b.y);
            s[6] = (short)f2bf(b.z); s[7] = (short)f2bf(b.w);
            int off = (r * 128 + f * 16) ^ ((r & 7) << 4);
            *reinterpret_cast<short8*>((char*)buf + off) = s;
        }
    }
};

// ---- per-tile fragment read + MFMA over one 64-k LDS tile ------------------
template<int BM, int WM, int WN, int FM>
__device__ __forceinline__ void mfma_tile(const unsigned short* Abuf,
    const unsigned short* Bbuf, f32x4 (&acc)[FM][4], int wr_, int wc, int lane)
{
#pragma unroll
    for (int kk = 0; kk < 2; ++kk) {
        short8 a[FM], b[4];
#pragma unroll
        for (int fi = 0; fi < FM; ++fi) {
            const int rA = wr_ * (BM / WM) + fi * 16 + (lane & 15);
            const int off = (rA * 128 + kk * 64 + (lane >> 4) * 16) ^ ((rA & 7) << 4);
            a[fi] = *reinterpret_cast<const short8*>((const char*)Abuf + off);
        }
#pragma unroll
        for (int fj = 0; fj < 4; ++fj) {
            const int rB = wc * 64 + fj * 16 + (lane & 15);
            const int off = (rB * 128 + kk * 64 + (lane >> 4) * 16) ^ ((rB & 7) << 4);
            b[fj] = *reinterpret_cast<const short8*>((const char*)Bbuf + off);
        }
#pragma unroll
        for (int fi = 0; fi < FM; ++fi)
#pragma unroll
            for (int fj = 0; fj < 4; ++fj)
                acc[fi][fj] = __builtin_amdgcn_mfma_f32_16x16x32_bf16(
                    a[fi], b[fj], acc[fi][fj], 0, 0, 0);
    }
}

// ---- 2-barrier staged GEMM: acc = A[32 x din] @ W[DOUT x din]^T (bf16 A) ---
template<int DOUT>
__device__ __forceinline__ void bulk_gemm_bf(const unsigned short* __restrict__ Av,
    const unsigned short* __restrict__ W, f32x4 (&acc)[DOUT / 128][4],
    unsigned short* Abuf, unsigned short* Bbuf, int din, int t)
{
    constexpr int WN = DOUT / 64, WM = 4 / WN, FM = DOUT / 128;
    const int wv = t >> 6, lane = t & 63, wr_ = wv / WN, wc = wv % WN;
    const int nt = din >> 6;
#pragma unroll
    for (int fi = 0; fi < FM; ++fi)
#pragma unroll
        for (int fj = 0; fj < 4; ++fj) acc[fi][fj] = (f32x4){0.f, 0.f, 0.f, 0.f};
    RegsBF<32> arb; RegsBF<DOUT> brg;
    arb.load(Av, din, 0, 0, t);
    brg.load(W, din, 0, 0, t);
    for (int kt = 0; kt < nt; ++kt) {
        if (kt) __syncthreads();
        arb.store(Abuf, t);
        brg.store(Bbuf, t);
        __syncthreads();
        if (kt + 1 < nt) {
            const int kn = (kt + 1) * 64;
            arb.load(Av, din, 0, kn, t);
            brg.load(W, din, 0, kn, t);
        }
        mfma_tile<32, WM, WN, FM>(Abuf, Bbuf, acc, wr_, wc, lane);
    }
}

// ---- proj epilogues: YT (bf16 transposed) + T (fp32 column sums) -----------
template<int DOUT>
__device__ __forceinline__ void proj_epilogue(const f32x4 (&acc)[DOUT / 128][4],
    unsigned short* __restrict__ YT, float* __restrict__ Tg, int i0,
    float* Tred, int t)
{
    constexpr int WN = DOUT / 64, WM = 4 / WN, FM = DOUT / 128;
    const int wv = t >> 6, lane = t & 63, wr_ = wv / WN, wc = wv % WN;
#pragma unroll
    for (int fi = 0; fi < FM; ++fi)
#pragma unroll
        for (int fj = 0; fj < 4; ++fj) {
            const int rl0 = wr_ * (32 / WM) + fi * 16 + ((lane >> 4) << 2);
            const int cl  = wc * 64 + fj * 16 + (lane & 15);
            ushort4 y;
            y.x = f2bf(acc[fi][fj][0]); y.y = f2bf(acc[fi][fj][1]);
            y.z = f2bf(acc[fi][fj][2]); y.w = f2bf(acc[fi][fj][3]);
            *reinterpret_cast<ushort4*>(YT + (size_t)cl * KROWS + i0 + rl0) = y;
        }
    float v[4];
#pragma unroll
    for (int fj = 0; fj < 4; ++fj) {
        float s = 0.f;
#pragma unroll
        for (int fi = 0; fi < FM; ++fi)
#pragma unroll
            for (int reg = 0; reg < 4; ++reg) s += acc[fi][fj][reg];
        s += __shfl_xor(s, 16);
        s += __shfl_xor(s, 32);
        v[fj] = s;
    }
    if (lane < 16) {
#pragma unroll
        for (int fj = 0; fj < 4; ++fj)
            Tred[wr_ * DOUT + wc * 64 + fj * 16 + lane] = v[fj];
    }
    __syncthreads();
    if (t < DOUT) {
        float s = Tred[t];
        if constexpr (WM == 2) s += Tred[DOUT + t];
        Tg[t] = s;
    }
}

// ---------------------------------------------------------------------------
// Proj body (prep only): dbuf-pipelined, fp32 A and B.
// ---------------------------------------------------------------------------
__device__ __forceinline__ void proj1_dbuf(const float* __restrict__ flow,
    const float* __restrict__ wl1, unsigned short* __restrict__ YT1,
    float* __restrict__ Tg, int i0, int t,
    unsigned short* Ab0, unsigned short* Ab1,
    unsigned short* Bb0, unsigned short* Bb1, float* Tred)
{
    const int wv = t >> 6, lane = t & 63, wr_ = wv >> 1, wc = wv & 1;
    f32x4 acc[1][4];
#pragma unroll
    for (int fj = 0; fj < 4; ++fj) acc[0][fj] = (f32x4){0.f, 0.f, 0.f, 0.f};
    RegsF32<32> ar; RegsF32<128> br;
    ar.load(flow, 1024, i0, 0, t);
    br.load(wl1, 1024, 0, 0, t);
    ar.store(Ab0, t); br.store(Bb0, t);
    ar.load(flow, 1024, i0, 64, t);
    br.load(wl1, 1024, 0, 64, t);
    __syncthreads();
    for (int kt = 0; kt < 16; ++kt) {
        const unsigned short* Ac = (kt & 1) ? Ab1 : Ab0;
        const unsigned short* Bc = (kt & 1) ? Bb1 : Bb0;
        mfma_tile<32, 2, 2, 1>(Ac, Bc, acc, wr_, wc, lane);
        if (kt + 1 < 16) {
            unsigned short* An = (kt & 1) ? Ab0 : Ab1;
            unsigned short* Bn = (kt & 1) ? Bb0 : Bb1;
            ar.store(An, t); br.store(Bn, t);
            if (kt + 2 < 16) {
                ar.load(flow, 1024, i0, (kt + 2) * 64, t);
                br.load(wl1, 1024, 0, (kt + 2) * 64, t);
            }
        }
        __syncthreads();
    }
    proj_epilogue<128>(acc, YT1, Tg, i0, Tred, t);
}

// ---------------------------------------------------------------------------
// prep: blocks [0,32) proj1 -> YT1 + T1; blocks [32,352) weight cvt; scalar.
// ---------------------------------------------------------------------------
__global__ __launch_bounds__(256, 2)
void prep_kernel(const float* __restrict__ flow, const float* __restrict__ wl1,
                 const float* __restrict__ wr1, const float* __restrict__ wl2,
                 const float* __restrict__ wr2, const float* __restrict__ wl3,
                 const float* __restrict__ wr3, const float* __restrict__ wl4,
                 const float* __restrict__ wr4,
                 unsigned short* __restrict__ wbf,
                 unsigned short* __restrict__ YT1, float* __restrict__ T1,
                 float* __restrict__ outscalar)
{
    __shared__ unsigned short Ab0[32 * 64], Ab1[32 * 64];
    __shared__ unsigned short Bb0[128 * 64], Bb1[128 * 64];
    __shared__ float Tred[256];
    const int t = threadIdx.x, bid = blockIdx.x;
    if (bid >= 32) {
        if (bid == 32 && t == 0) outscalar[0] = 1.0f;
        int g = (bid - 32) * 1024 + t * 4;
        const float* src; int off;
        if      (g < 131072) { src = wr1; off = g; }
        else if (g < 163840) { src = wl2; off = g - 131072; }
        else if (g < 196608) { src = wr2; off = g - 163840; }
        else if (g < 229376) { src = wl3; off = g - 196608; }
        else if (g < 262144) { src = wr3; off = g - 229376; }
        else if (g < 294912) { src = wl4; off = g - 262144; }
        else                 { src = wr4; off = g - 294912; }
        float4 v = *reinterpret_cast<const float4*>(src + off);
        ushort4 o4;
        o4.x = f2bf(v.x); o4.y = f2bf(v.y); o4.z = f2bf(v.z); o4.w = f2bf(v.w);
        *reinterpret_cast<ushort4*>(wbf + g) = o4;
        return;
    }
    proj1_dbuf(flow, wl1, YT1, T1 + bid * 128, bid * 32, t,
               Ab0, Ab1, Bb0, Bb1, Tred);
}

// ---------------------------------------------------------------------------
// main_L.  MODE 1: bf16 x out (+ head: next-layer proj).  MODE 2: relu->fp32.
// DNEXT > 0: head blocks re-read their own just-stored x rows (post-barrier,
// L2) and run the staged proj for the next layer -> YTn + Tn.
// ---------------------------------------------------------------------------
template<int DOUT, int MODE, bool AFP32, int MINW, int DNEXT>
__global__ __launch_bounds__(256, MINW)
void mfma_gemm(const void* __restrict__ Xv,
               const unsigned short* __restrict__ W,
               const float* __restrict__ bias,
               const unsigned short* __restrict__ YT,  // (DOUT, 1024) bf16
               const float* __restrict__ Tbuf,         // (32, DOUT) fp32
               float* __restrict__ outf,
               unsigned short* __restrict__ outb,
               int din,
               const unsigned short* __restrict__ Wn,  // next wl (bf16)
               unsigned short* __restrict__ YTn, float* __restrict__ Tn)
{
    constexpr int BM = 32, BN = DOUT;
    constexpr int WN = DOUT / 64, WM = 4 / WN, FM = DOUT / 128;
    constexpr int BB = (DNEXT > BN ? DNEXT : BN);
    __shared__ unsigned short Abuf[BM * 64];
    __shared__ unsigned short Bbuf[BB * 64];
    __shared__ float ssred[WN * BM];
    __shared__ float Tred[256];

    const int t = threadIdx.x, wvid = t >> 6, lane = t & 63;
    const int wr_ = wvid / WN, wc = wvid % WN;
    const int i0 = blockIdx.x * BM;
    const int nt = din >> 6;
    const bool hasagg = (i0 < KROWS);

    f32x4 agg[FM][4];
#pragma unroll
    for (int fi = 0; fi < FM; ++fi)
#pragma unroll
        for (int fj = 0; fj < 4; ++fj) agg[fi][fj] = (f32x4){0.f, 0.f, 0.f, 0.f};

    if (hasagg) {
        // ---- P[col] = sum_{m'<m} T[m'][col] ----
        const int m = i0 >> 5;
        const int colb = wc * 64 + (lane & 15);
        float Pv[4] = {0.f, 0.f, 0.f, 0.f}, Pa[4] = {0.f, 0.f, 0.f, 0.f};
        int mp = 0;
        for (; mp + 1 < m; mp += 2) {
            const float* T0 = Tbuf + (size_t)mp * DOUT + colb;
            const float* T1p = T0 + DOUT;
#pragma unroll
            for (int fj = 0; fj < 4; ++fj) {
                Pv[fj] += T0[fj * 16];
                Pa[fj] += T1p[fj * 16];
            }
        }
        if (mp < m) {
            const float* T0 = Tbuf + (size_t)mp * DOUT + colb;
#pragma unroll
            for (int fj = 0; fj < 4; ++fj) Pv[fj] += T0[fj * 16];
        }
#pragma unroll
        for (int fj = 0; fj < 4; ++fj) Pv[fj] += Pa[fj];

        // ---- local triangular: ONE staged step over YT cols [base,base+64) -
        const int base = i0 & ~63;
        RegsBF<BN> sb;
        sb.load(YT, KROWS, 0, base, t);
        sb.store(Bbuf, t);
        __syncthreads();
#pragma unroll
        for (int kk = 0; kk < 2; ++kk) {
            const int jb = base + kk * 32 + ((lane >> 4) << 3);
            short8 a[FM], b[4];
#pragma unroll
            for (int fi = 0; fi < FM; ++fi) {
                const int irow = i0 + wr_ * (BM / WM) + fi * 16 + (lane & 15);
#pragma unroll
                for (int e = 0; e < 8; ++e)
                    a[fi][e] = (short)((jb + e >= i0 && jb + e < irow) ? 0x3F80 : 0);
            }
#pragma unroll
            for (int fj = 0; fj < 4; ++fj) {
                const int rB = wc * 64 + fj * 16 + (lane & 15);
                const int off = (rB * 128 + kk * 64 + (lane >> 4) * 16) ^ ((rB & 7) << 4);
                b[fj] = *reinterpret_cast<const short8*>((const char*)Bbuf + off);
            }
#pragma unroll
            for (int fi = 0; fi < FM; ++fi)
#pragma unroll
                for (int fj = 0; fj < 4; ++fj)
                    agg[fi][fj] = __builtin_amdgcn_mfma_f32_16x16x32_bf16(
                        a[fi], b[fj], agg[fi][fj], 0, 0, 0);
        }
#pragma unroll
        for (int fi = 0; fi < FM; ++fi)
#pragma unroll
            for (int reg = 0; reg < 4; ++reg) {
                const int i_abs = i0 + wr_ * (BM / WM) + fi * 16 + ((lane >> 4) << 2) + reg;
                const float inv = 1.0f / (float)(i_abs > 1 ? i_abs : 1);
#pragma unroll
                for (int fj = 0; fj < 4; ++fj)
                    agg[fi][fj][reg] = (agg[fi][fj][reg] + Pv[fj]) * inv;
            }
        __syncthreads();                        // Bbuf free before bulk
    }

    // ---- bulk GEMM (R13 2-barrier staged core) ----
    f32x4 acc[FM][4];
#pragma unroll
    for (int fi = 0; fi < FM; ++fi)
#pragma unroll
        for (int fj = 0; fj < 4; ++fj) acc[fi][fj] = (f32x4){0.f, 0.f, 0.f, 0.f};

    RegsBF<BN> brg;
    RegsF32<BM> arf;
    RegsBF<BM> arb;
    if (AFP32) arf.load((const float*)Xv, din, i0, 0, t);
    else       arb.load((const unsigned short*)Xv, din, i0, 0, t);
    brg.load(W, din, 0, 0, t);

    for (int kt = 0; kt < nt; ++kt) {
        if (kt) __syncthreads();
        if (AFP32) arf.store(Abuf, t); else arb.store(Abuf, t);
        brg.store(Bbuf, t);
        __syncthreads();
        if (kt + 1 < nt) {
            int kn = (kt + 1) * 64;
            if (AFP32) arf.load((const float*)Xv, din, i0, kn, t);
            else       arb.load((const unsigned short*)Xv, din, i0, kn, t);
            brg.load(W, din, 0, kn, t);
        }
        mfma_tile<BM, WM, WN, FM>(Abuf, Bbuf, acc, wr_, wc, lane);
    }

    float bb[4];
#pragma unroll
    for (int fj = 0; fj < 4; ++fj) bb[fj] = bias[wc * 64 + fj * 16 + (lane & 15)];

#pragma unroll
    for (int fi = 0; fi < FM; ++fi)
#pragma unroll
        for (int fj = 0; fj < 4; ++fj)
#pragma unroll
            for (int reg = 0; reg < 4; ++reg)
                acc[fi][fj][reg] += bb[fj] + agg[fi][fj][reg];

    float sstot[FM][4];
#pragma unroll
    for (int fi = 0; fi < FM; ++fi)
#pragma unroll
        for (int reg = 0; reg < 4; ++reg) {
            float s = 0.f;
#pragma unroll
            for (int fj = 0; fj < 4; ++fj) {
                float v = acc[fi][fj][reg];
                s += v * v;
            }
#pragma unroll
            for (int m2 = 8; m2 >= 1; m2 >>= 1) s += __shfl_xor(s, m2);
            if ((lane & 15) == 0) {
                int rl = wr_ * (BM / WM) + fi * 16 + ((lane >> 4) << 2) + reg;
                ssred[wc * BM + rl] = s;
            }
        }
    __syncthreads();
#pragma unroll
    for (int fi = 0; fi < FM; ++fi)
#pragma unroll
        for (int reg = 0; reg < 4; ++reg) {
            int rl = wr_ * (BM / WM) + fi * 16 + ((lane >> 4) << 2) + reg;
            float s = 0.f;
#pragma unroll
            for (int c = 0; c < WN; ++c) s += ssred[c * BM + rl];
            sstot[fi][reg] = 1.0f / fmaxf(sqrtf(s), 1e-12f);
        }

#pragma unroll
    for (int fi = 0; fi < FM; ++fi)
#pragma unroll
        for (int fj = 0; fj < 4; ++fj)
#pragma unroll
            for (int reg = 0; reg < 4; ++reg) {
                int rl = wr_ * (BM / WM) + fi * 16 + ((lane >> 4) << 2) + reg;
                int cl = wc * 64 + fj * 16 + (lane & 15);
                float v = acc[fi][fj][reg] * sstot[fi][reg];
                if (MODE == 2) {
                    v = fmaxf(v, 0.f);
                    outf[(size_t)(i0 + rl) * DOUT + cl] = v;
                } else {
                    outb[(size_t)(i0 + rl) * DOUT + cl] = f2bf(v);
                }
            }

    // ---- head: next-layer proj on own just-stored rows ----
    if constexpr (DNEXT > 0) {
        if (hasagg) {
            __syncthreads();        // drain x stores (vmcnt0 at barrier)
            f32x4 acc2[DNEXT / 128][4];
            bulk_gemm_bf<DNEXT>(outb + (size_t)i0 * DOUT, Wn, acc2,
                                Abuf, Bbuf, DOUT, t);
            __syncthreads();        // Tred reuse safety (after ssred phase)
            proj_epilogue<DNEXT>(acc2, YTn, Tn + (i0 >> 5) * DNEXT, i0, Tred, t);
        }
    }
}

extern "C" void kernel_launch(void* const* d_in, const int* in_sizes, int n_in,
                              void* d_out, int out_size, void* d_ws, size_t ws_size,
                              hipStream_t stream)
{
    const float* flow = (const float*)d_in[0];
    const float* wl1 = (const float*)d_in[1];
    const float* bl1 = (const float*)d_in[2];
    const float* wr1 = (const float*)d_in[3];
    const float* wl2 = (const float*)d_in[4];
    const float* bl2 = (const float*)d_in[5];
    const float* wr2 = (const float*)d_in[6];
    const float* wl3 = (const float*)d_in[7];
    const float* bl3 = (const float*)d_in[8];
    const float* wr3 = (const float*)d_in[9];
    const float* wl4 = (const float*)d_in[10];
    const float* bl4 = (const float*)d_in[11];
    const float* wr4 = (const float*)d_in[12];
    float* out = (float*)d_out;

    char* p = (char*)d_ws;
    unsigned short* wbf = (unsigned short*)p;  p += 1 << 20;
    unsigned short* xA  = (unsigned short*)p;  p += (size_t)NROWS * 128 * 2;
    unsigned short* xB  = (unsigned short*)p;  p += (size_t)NROWS * 256 * 2;
    unsigned short* YT1 = (unsigned short*)p;  p += (size_t)128 * KROWS * 2;
    unsigned short* YT2 = (unsigned short*)p;  p += (size_t)256 * KROWS * 2;
    unsigned short* YT3 = (unsigned short*)p;  p += (size_t)128 * KROWS * 2;
    unsigned short* YT4 = (unsigned short*)p;  p += (size_t)256 * KROWS * 2;
    float* T1 = (float*)p;                     p += (size_t)32 * 128 * 4;
    float* T2 = (float*)p;                     p += (size_t)32 * 256 * 4;
    float* T3 = (float*)p;                     p += (size_t)32 * 128 * 4;
    float* T4 = (float*)p;

    const unsigned short* wr1b = wbf;
    const unsigned short* wl2b = wbf + 131072;
    const unsigned short* wr2b = wbf + 163840;
    const unsigned short* wl3b = wbf + 196608;
    const unsigned short* wr3b = wbf + 229376;
    const unsigned short* wl4b = wbf + 262144;
    const unsigned short* wr4b = wbf + 294912;

    // D1: cvt + proj1 (+ tuple scalar)
    prep_kernel<<<352, 256, 0, stream>>>(flow, wl1, wr1, wl2, wr2, wl3, wr3,
                                         wl4, wr4, wbf, YT1, T1,
                                         out + (size_t)NROWS * 256);
    // D2: main L1 (din=1024, fp32 A); heads emit proj2 -> YT2,T2
    mfma_gemm<128, 1, true , 4, 256><<<1024, 256, 0, stream>>>(
        flow, wr1b, bl1, YT1, T1, nullptr, xA, 1024, wl2b, YT2, T2);
    // D3: main L2 (din=128); heads emit proj3 -> YT3,T3
    mfma_gemm<256, 1, false, 3, 128><<<1024, 256, 0, stream>>>(
        xA, wr2b, bl2, YT2, T2, nullptr, xB, 128, wl3b, YT3, T3);
    // D4: main L3 (din=256); heads emit proj4 -> YT4,T4
    mfma_gemm<128, 1, false, 4, 256><<<1024, 256, 0, stream>>>(
        xB, wr3b, bl3, YT3, T3, nullptr, xA, 256, wl4b, YT4, T4);
    // D5: main L4 (din=128) + relu -> fp32 out
    mfma_gemm<256, 2, false, 3, 0><<<1024, 256, 0, stream>>>(
        xA, wr4b, bl4, YT4, T4, out, nullptr, 128, nullptr, nullptr, nullptr);
}